// Round 4
// baseline (297.646 us; speedup 1.0000x reference)
//
#include <hip/hip_runtime.h>
#include <math.h>

// ResidualGATLayer on MI355X.
// Inputs: x[f32 N*128], edge_index[int 2*E], W[f32 128*128],
// a_src[f32 4*32], a_dst[f32 4*32], bias[f32 128]. Output f32 N*128.

#define CH 128

typedef short bf16x8 __attribute__((ext_vector_type(8)));
typedef float f32x4 __attribute__((ext_vector_type(4)));

__device__ __forceinline__ short f2bf(float f) {
    unsigned int u = __builtin_bit_cast(unsigned int, f);
    u += 0x7FFFu + ((u >> 16) & 1u);          // RNE
    return (short)(u >> 16);
}
__device__ __forceinline__ float bflo(unsigned int u) {
    return __builtin_bit_cast(float, u << 16);
}
__device__ __forceinline__ float bfhi(unsigned int u) {
    return __builtin_bit_cast(float, u & 0xffff0000u);
}

// ---------------- Kernel 0: W -> bf16 transposed (Wt[n][k]) ----------------
__global__ void conv_w(const float* __restrict__ W, short* __restrict__ Wbf) {
    int i = blockIdx.x * 256 + threadIdx.x;       // 16384
    if (i < CH * CH) {
        int k = i >> 7, n = i & 127;
        Wbf[n * CH + k] = f2bf(W[i]);
    }
}

// ---------------- Kernel 1: h(bf16) = x @ W via MFMA, fused alpha ----------------
// 256 thr = 4 waves; 128 nodes/block; wave w -> rows [w*32, w*32+32) (2 m-tiles).
__global__ __launch_bounds__(256) void gemm_mfma(
    const float* __restrict__ x, const short* __restrict__ Wbf,
    const float* __restrict__ a_src, const float* __restrict__ a_dst,
    unsigned short* __restrict__ hb, float* __restrict__ as_, float* __restrict__ ad_,
    int N)
{
    __shared__ short Wl[CH * CH];                 // 32 KiB, swizzled [n][k']
    for (int v = threadIdx.x; v < 2048; v += 256) {
        int n = v >> 4, k8 = v & 15;
        *(bf16x8*)&Wl[n * CH + ((k8 ^ (n & 7)) << 3)] = *(const bf16x8*)&Wbf[v * 8];
    }
    const int w = threadIdx.x >> 6, l = threadIdx.x & 63;
    const int lr = l & 15, lg = l >> 4;
    const int base = blockIdx.x * 128 + w * 32;

    float asr[8], adr[8];
    #pragma unroll
    for (int nt = 0; nt < 8; ++nt) {
        asr[nt] = a_src[nt * 16 + lr];
        adr[nt] = a_dst[nt * 16 + lr];
    }
    __syncthreads();

    // A-frags: row = lr, k = lg*8 + j per 32-wide K-step
    bf16x8 afr[2][4];
    #pragma unroll
    for (int mt = 0; mt < 2; ++mt) {
        int arow = base + mt * 16 + lr;
        if (arow >= N) arow = N - 1;
        const float* xr = &x[(size_t)arow * CH + lg * 8];
        #pragma unroll
        for (int ks = 0; ks < 4; ++ks) {
            float4 p0 = *(const float4*)&xr[ks * 32];
            float4 p1 = *(const float4*)&xr[ks * 32 + 4];
            afr[mt][ks][0] = f2bf(p0.x); afr[mt][ks][1] = f2bf(p0.y);
            afr[mt][ks][2] = f2bf(p0.z); afr[mt][ks][3] = f2bf(p0.w);
            afr[mt][ks][4] = f2bf(p1.x); afr[mt][ks][5] = f2bf(p1.y);
            afr[mt][ks][6] = f2bf(p1.z); afr[mt][ks][7] = f2bf(p1.w);
        }
    }

    f32x4 acc[2][8];
    #pragma unroll
    for (int mt = 0; mt < 2; ++mt)
        #pragma unroll
        for (int nt = 0; nt < 8; ++nt) acc[mt][nt] = (f32x4){0.f, 0.f, 0.f, 0.f};

    #pragma unroll
    for (int ks = 0; ks < 4; ++ks) {
        #pragma unroll
        for (int nt = 0; nt < 8; ++nt) {
            bf16x8 bfr = *(const bf16x8*)&Wl[(nt * 16 + lr) * CH + (((ks * 4 + lg) ^ (lr & 7)) << 3)];
            acc[0][nt] = __builtin_amdgcn_mfma_f32_16x16x32_bf16(afr[0][ks], bfr, acc[0][nt], 0, 0, 0);
            acc[1][nt] = __builtin_amdgcn_mfma_f32_16x16x32_bf16(afr[1][ks], bfr, acc[1][nt], 0, 0, 0);
        }
    }

    // C/D: col = lr, row = lg*4 + r
    #pragma unroll
    for (int mt = 0; mt < 2; ++mt) {
        const int rbase = base + mt * 16 + lg * 4;
        #pragma unroll
        for (int nt = 0; nt < 8; ++nt) {
            #pragma unroll
            for (int r = 0; r < 4; ++r) {
                int orow = rbase + r;
                if (orow < N) hb[(size_t)orow * CH + nt * 16 + lr] = (unsigned short)f2bf(acc[mt][nt][r]);
            }
        }
        #pragma unroll
        for (int r = 0; r < 4; ++r) {
            float sv[4] = {0.f, 0.f, 0.f, 0.f}, dv[4] = {0.f, 0.f, 0.f, 0.f};
            #pragma unroll
            for (int nt = 0; nt < 8; ++nt) {
                float vv = acc[mt][nt][r];
                sv[nt >> 1] = fmaf(vv, asr[nt], sv[nt >> 1]);
                dv[nt >> 1] = fmaf(vv, adr[nt], dv[nt >> 1]);
            }
            #pragma unroll
            for (int m = 1; m < 16; m <<= 1) {
                #pragma unroll
                for (int hh = 0; hh < 4; ++hh) {
                    sv[hh] += __shfl_xor(sv[hh], m, 64);
                    dv[hh] += __shfl_xor(dv[hh], m, 64);
                }
            }
            int orow = rbase + r;
            if (lr == 0 && orow < N) {
                *(float4*)&as_[orow * 4] = make_float4(sv[0], sv[1], sv[2], sv[3]);
                *(float4*)&ad_[orow * 4] = make_float4(dv[0], dv[1], dv[2], dv[3]);
            }
        }
    }
}

// ---------------- CSR build ----------------
__global__ void init_deg(int* __restrict__ deg, int* __restrict__ cursor, int N) {
    int i = blockIdx.x * blockDim.x + threadIdx.x;
    if (i < N) { deg[i] = 1; cursor[i] = 0; }     // 1 = self loop
}

__global__ void hist(const int* __restrict__ dst, int* __restrict__ deg, int E) {
    int i = blockIdx.x * blockDim.x + threadIdx.x;
    int e0 = i * 4;
    if (e0 + 3 < E) {
        int4 d = *(const int4*)&dst[e0];
        atomicAdd(&deg[d.x], 1); atomicAdd(&deg[d.y], 1);
        atomicAdd(&deg[d.z], 1); atomicAdd(&deg[d.w], 1);
    } else {
        for (int c = 0; c < 4; ++c)
            if (e0 + c < E) atomicAdd(&deg[dst[e0 + c]], 1);
    }
}

// Single-block scan: 1024 threads x 52 contiguous elems, 2 barriers total.
__global__ __launch_bounds__(1024) void scan_deg(const int* __restrict__ deg,
                                                 int* __restrict__ row_start, int N)
{
    __shared__ int wsum[16];
    const int t = threadIdx.x;
    const int lane = t & 63, w = t >> 6;
    const int PT = 52;                             // 1024*52 >= 50000
    const int base = t * PT;
    int local = 0;
    for (int i = 0; i < PT; i += 4) {
        int idx = base + i;
        if (idx + 3 < N) {
            int4 v4 = *(const int4*)&deg[idx];
            local += v4.x + v4.y + v4.z + v4.w;
        } else {
            for (int c = 0; c < 4; ++c) if (idx + c < N) local += deg[idx + c];
        }
    }
    int s = local;
    #pragma unroll
    for (int off = 1; off < 64; off <<= 1) {
        int u = __shfl_up(s, off, 64);
        if (lane >= off) s += u;
    }
    if (lane == 63) wsum[w] = s;
    __syncthreads();
    if (t < 16) {
        int tt = wsum[t];
        #pragma unroll
        for (int off = 1; off < 16; off <<= 1) {
            int u = __shfl_up(tt, off, 64);
            if (t >= off) tt += u;
        }
        wsum[t] = tt;
    }
    __syncthreads();
    int p = s - local + ((w > 0) ? wsum[w - 1] : 0);
    if (t == 0) row_start[0] = 0;
    for (int i = 0; i < PT; ++i) {
        int idx = base + i;
        if (idx < N) { p += deg[idx]; row_start[idx + 1] = p; }
    }
}

__global__ void scatter_edges(const int* __restrict__ src, const int* __restrict__ dst,
                              const int* __restrict__ row_start, int* __restrict__ cursor,
                              int* __restrict__ esrc, int E, int N)
{
    int i = blockIdx.x * blockDim.x + threadIdx.x;
    int total = E + N;
    if (i >= total) return;
    int s, d;
    if (i < E) { s = src[i]; d = dst[i]; }
    else       { s = i - E;  d = s; }              // self loops
    int pos = row_start[d] + atomicAdd(&cursor[d], 1);
    esrc[pos] = s;
}

// ---------------- Kernel 5: per-node softmax-weighted aggregation ----------------
// One wave per dst node. Lane owns channels {2*lane, 2*lane+1} -> one head/lane.
// h gathered in bf16 (4 B/lane/edge).
__global__ __launch_bounds__(256) void gat_aggregate(
    const unsigned short* __restrict__ hb, const float* __restrict__ as_,
    const float* __restrict__ ad_, const int* __restrict__ row_start,
    const int* __restrict__ esrc, const float* __restrict__ bias,
    const float* __restrict__ x, float* __restrict__ out, int N)
{
    int wid = blockIdx.x * 4 + (threadIdx.x >> 6);
    int lane = threadIdx.x & 63;
    if (wid >= N) return;
    const int head = lane >> 4;                    // channel 2*lane -> head (2*lane)>>5
    const float adv = ad_[wid * 4 + head];

    float den = 0.f, acc0 = 0.f, acc1 = 0.f;
    const int jb = row_start[wid], je = row_start[wid + 1];
    int j = jb;
    for (; j + 3 < je; j += 4) {
        int s0 = esrc[j], s1 = esrc[j + 1], s2 = esrc[j + 2], s3 = esrc[j + 3];
        float e0 = as_[s0 * 4 + head] + adv;
        float e1 = as_[s1 * 4 + head] + adv;
        float e2 = as_[s2 * 4 + head] + adv;
        float e3 = as_[s3 * 4 + head] + adv;
        unsigned int h0 = *(const unsigned int*)&hb[(size_t)s0 * CH + 2 * lane];
        unsigned int h1 = *(const unsigned int*)&hb[(size_t)s1 * CH + 2 * lane];
        unsigned int h2 = *(const unsigned int*)&hb[(size_t)s2 * CH + 2 * lane];
        unsigned int h3 = *(const unsigned int*)&hb[(size_t)s3 * CH + 2 * lane];
        e0 = (e0 < 0.f) ? 0.2f * e0 : e0;  e1 = (e1 < 0.f) ? 0.2f * e1 : e1;
        e2 = (e2 < 0.f) ? 0.2f * e2 : e2;  e3 = (e3 < 0.f) ? 0.2f * e3 : e3;
        float p0 = __expf(e0), p1 = __expf(e1), p2 = __expf(e2), p3 = __expf(e3);
        den += (p0 + p1) + (p2 + p3);
        acc0 = fmaf(p0, bflo(h0), fmaf(p1, bflo(h1), fmaf(p2, bflo(h2), fmaf(p3, bflo(h3), acc0))));
        acc1 = fmaf(p0, bfhi(h0), fmaf(p1, bfhi(h1), fmaf(p2, bfhi(h2), fmaf(p3, bfhi(h3), acc1))));
    }
    for (; j < je; ++j) {
        int s0 = esrc[j];
        float e0 = as_[s0 * 4 + head] + adv;
        unsigned int h0 = *(const unsigned int*)&hb[(size_t)s0 * CH + 2 * lane];
        e0 = (e0 < 0.f) ? 0.2f * e0 : e0;
        float p0 = __expf(e0);
        den += p0;
        acc0 = fmaf(p0, bflo(h0), acc0);
        acc1 = fmaf(p0, bfhi(h0), acc1);
    }
    float inv = 1.f / (den + 1e-16f);
    float2 bv = *(const float2*)&bias[2 * lane];
    float o0 = acc0 * inv + bv.x;
    float o1 = acc1 * inv + bv.y;
    o0 = (o0 > 0.f) ? o0 : expm1f(o0);             // ELU
    o1 = (o1 > 0.f) ? o1 : expm1f(o1);
    float2 xv = *(const float2*)&x[(size_t)wid * CH + 2 * lane];
    float2 ov; ov.x = o0 + xv.x; ov.y = o1 + xv.y;
    *(float2*)&out[(size_t)wid * CH + 2 * lane] = ov;
}

extern "C" void kernel_launch(void* const* d_in, const int* in_sizes, int n_in,
                              void* d_out, int out_size, void* d_ws, size_t ws_size,
                              hipStream_t stream) {
    const float* x     = (const float*)d_in[0];
    const int*   ei    = (const int*)d_in[1];
    const float* W     = (const float*)d_in[2];
    const float* a_src = (const float*)d_in[3];
    const float* a_dst = (const float*)d_in[4];
    const float* bias  = (const float*)d_in[5];
    float* out = (float*)d_out;

    const int N = in_sizes[0] / CH;       // 50000
    const int E = in_sizes[1] / 2;        // 800000
    const int* src = ei;
    const int* dst = ei + E;

    unsigned short* hb = (unsigned short*)d_ws;            // N*128 bf16
    float* as_ = (float*)(hb + (size_t)N * CH);            // N*4
    float* ad_ = as_ + (size_t)N * 4;                      // N*4
    short* Wbf = (short*)(ad_ + (size_t)N * 4);            // 128*128
    int* deg       = (int*)(Wbf + CH * CH);
    int* cursor    = deg + N;
    int* row_start = cursor + N;
    int* esrc      = row_start + (N + 1);

    conv_w<<<(CH * CH + 255) / 256, 256, 0, stream>>>(W, Wbf);
    init_deg<<<(N + 255) / 256, 256, 0, stream>>>(deg, cursor, N);
    gemm_mfma<<<(N + 127) / 128, 256, 0, stream>>>(x, Wbf, a_src, a_dst, hb, as_, ad_, N);
    hist<<<(E / 4 + 255) / 256, 256, 0, stream>>>(dst, deg, E);
    scan_deg<<<1, 1024, 0, stream>>>(deg, row_start, N);
    scatter_edges<<<(E + N + 255) / 256, 256, 0, stream>>>(src, dst, row_start, cursor, esrc, E, N);
    gat_aggregate<<<(N + 3) / 4, 256, 0, stream>>>(hb, as_, ad_, row_start, esrc, bias, x, out, N);
}

// Round 5
// 230.340 us; speedup vs baseline: 1.2922x; 1.2922x over previous
//
#include <hip/hip_runtime.h>
#include <math.h>

// ResidualGATLayer on MI355X.
// Inputs: x[f32 N*128], edge_index[int 2*E], W[f32 128*128],
// a_src[f32 4*32], a_dst[f32 4*32], bias[f32 128]. Output f32 N*128.

#define CH 128

typedef short bf16x8 __attribute__((ext_vector_type(8)));
typedef float f32x4 __attribute__((ext_vector_type(4)));

__device__ __forceinline__ short f2bf(float f) {
    unsigned int u = __builtin_bit_cast(unsigned int, f);
    u += 0x7FFFu + ((u >> 16) & 1u);          // RNE
    return (short)(u >> 16);
}
__device__ __forceinline__ float bflo(unsigned int u) {
    return __builtin_bit_cast(float, u << 16);
}
__device__ __forceinline__ float bfhi(unsigned int u) {
    return __builtin_bit_cast(float, u & 0xffff0000u);
}

// ---------------- Kernel 0: prep — W->bf16 transposed + deg/cursor init ----------------
__global__ void prep(const float* __restrict__ W, short* __restrict__ Wbf,
                     int* __restrict__ deg, int* __restrict__ cursor, int N) {
    int i = blockIdx.x * 256 + threadIdx.x;
    if (i < CH * CH) {
        int k = i >> 7, n = i & 127;
        Wbf[n * CH + k] = f2bf(W[i]);
    }
    if (i < N) { deg[i] = 1; cursor[i] = 0; }     // 1 = self loop
}

// ---------------- Kernel 1: h(bf16) = x @ W via MFMA, fused alpha ----------------
// 256 thr = 4 waves; 128 nodes/block; wave w -> rows [w*32, w*32+32) (2 m-tiles).
__global__ __launch_bounds__(256) void gemm_mfma(
    const float* __restrict__ x, const short* __restrict__ Wbf,
    const float* __restrict__ a_src, const float* __restrict__ a_dst,
    unsigned short* __restrict__ hb, float* __restrict__ as_, float* __restrict__ ad_,
    int N)
{
    __shared__ short Wl[CH * CH];                 // 32 KiB, swizzled [n][k']
    for (int v = threadIdx.x; v < 2048; v += 256) {
        int n = v >> 4, k8 = v & 15;
        *(bf16x8*)&Wl[n * CH + ((k8 ^ (n & 7)) << 3)] = *(const bf16x8*)&Wbf[v * 8];
    }
    const int w = threadIdx.x >> 6, l = threadIdx.x & 63;
    const int lr = l & 15, lg = l >> 4;
    const int base = blockIdx.x * 128 + w * 32;

    float asr[8], adr[8];
    #pragma unroll
    for (int nt = 0; nt < 8; ++nt) {
        asr[nt] = a_src[nt * 16 + lr];
        adr[nt] = a_dst[nt * 16 + lr];
    }
    __syncthreads();

    // A-frags: row = lr, k = lg*8 + j per 32-wide K-step
    bf16x8 afr[2][4];
    #pragma unroll
    for (int mt = 0; mt < 2; ++mt) {
        int arow = base + mt * 16 + lr;
        if (arow >= N) arow = N - 1;
        const float* xr = &x[(size_t)arow * CH + lg * 8];
        #pragma unroll
        for (int ks = 0; ks < 4; ++ks) {
            float4 p0 = *(const float4*)&xr[ks * 32];
            float4 p1 = *(const float4*)&xr[ks * 32 + 4];
            afr[mt][ks][0] = f2bf(p0.x); afr[mt][ks][1] = f2bf(p0.y);
            afr[mt][ks][2] = f2bf(p0.z); afr[mt][ks][3] = f2bf(p0.w);
            afr[mt][ks][4] = f2bf(p1.x); afr[mt][ks][5] = f2bf(p1.y);
            afr[mt][ks][6] = f2bf(p1.z); afr[mt][ks][7] = f2bf(p1.w);
        }
    }

    f32x4 acc[2][8];
    #pragma unroll
    for (int mt = 0; mt < 2; ++mt)
        #pragma unroll
        for (int nt = 0; nt < 8; ++nt) acc[mt][nt] = (f32x4){0.f, 0.f, 0.f, 0.f};

    #pragma unroll
    for (int ks = 0; ks < 4; ++ks) {
        #pragma unroll
        for (int nt = 0; nt < 8; ++nt) {
            bf16x8 bfr = *(const bf16x8*)&Wl[(nt * 16 + lr) * CH + (((ks * 4 + lg) ^ (lr & 7)) << 3)];
            acc[0][nt] = __builtin_amdgcn_mfma_f32_16x16x32_bf16(afr[0][ks], bfr, acc[0][nt], 0, 0, 0);
            acc[1][nt] = __builtin_amdgcn_mfma_f32_16x16x32_bf16(afr[1][ks], bfr, acc[1][nt], 0, 0, 0);
        }
    }

    // C/D: col = lr, row = lg*4 + r
    #pragma unroll
    for (int mt = 0; mt < 2; ++mt) {
        const int rbase = base + mt * 16 + lg * 4;
        #pragma unroll
        for (int nt = 0; nt < 8; ++nt) {
            #pragma unroll
            for (int r = 0; r < 4; ++r) {
                int orow = rbase + r;
                if (orow < N) hb[(size_t)orow * CH + nt * 16 + lr] = (unsigned short)f2bf(acc[mt][nt][r]);
            }
        }
        #pragma unroll
        for (int r = 0; r < 4; ++r) {
            float sv[4] = {0.f, 0.f, 0.f, 0.f}, dv[4] = {0.f, 0.f, 0.f, 0.f};
            #pragma unroll
            for (int nt = 0; nt < 8; ++nt) {
                float vv = acc[mt][nt][r];
                sv[nt >> 1] = fmaf(vv, asr[nt], sv[nt >> 1]);
                dv[nt >> 1] = fmaf(vv, adr[nt], dv[nt >> 1]);
            }
            #pragma unroll
            for (int m = 1; m < 16; m <<= 1) {
                #pragma unroll
                for (int hh = 0; hh < 4; ++hh) {
                    sv[hh] += __shfl_xor(sv[hh], m, 64);
                    dv[hh] += __shfl_xor(dv[hh], m, 64);
                }
            }
            int orow = rbase + r;
            if (lr == 0 && orow < N) {
                *(float4*)&as_[orow * 4] = make_float4(sv[0], sv[1], sv[2], sv[3]);
                *(float4*)&ad_[orow * 4] = make_float4(dv[0], dv[1], dv[2], dv[3]);
            }
        }
    }
}

// ---------------- CSR build ----------------
__global__ void hist(const int* __restrict__ dst, int* __restrict__ deg, int E) {
    int i = blockIdx.x * blockDim.x + threadIdx.x;
    int e0 = i * 4;
    if (e0 + 3 < E) {
        int4 d = *(const int4*)&dst[e0];
        atomicAdd(&deg[d.x], 1); atomicAdd(&deg[d.y], 1);
        atomicAdd(&deg[d.z], 1); atomicAdd(&deg[d.w], 1);
    } else {
        for (int c = 0; c < 4; ++c)
            if (e0 + c < E) atomicAdd(&deg[dst[e0 + c]], 1);
    }
}

// -------- 3-pass multi-block scan: 1024 elems/block (256 thr x int4) --------
__device__ __forceinline__ int4 load_deg4(const int* __restrict__ deg, int idx, int N) {
    int4 v = make_int4(0, 0, 0, 0);
    if (idx + 3 < N)      v = *(const int4*)&deg[idx];
    else if (idx < N) {
        v.x = deg[idx];
        if (idx + 1 < N) v.y = deg[idx + 1];
        if (idx + 2 < N) v.z = deg[idx + 2];
    }
    return v;
}

__global__ __launch_bounds__(256) void scan_p1(const int* __restrict__ deg,
                                               int* __restrict__ bsum, int N) {
    int t = threadIdx.x;
    int idx = blockIdx.x * 1024 + t * 4;
    int4 v = load_deg4(deg, idx, N);
    int s = v.x + v.y + v.z + v.w;
    #pragma unroll
    for (int off = 1; off < 64; off <<= 1) s += __shfl_xor(s, off, 64);
    __shared__ int ws[4];
    if ((t & 63) == 0) ws[t >> 6] = s;
    __syncthreads();
    if (t == 0) bsum[blockIdx.x] = ws[0] + ws[1] + ws[2] + ws[3];
}

// one wave, nb <= a few thousand (loops in chunks of 64 with carry)
__global__ void scan_p2(const int* __restrict__ bsum, int* __restrict__ bofs, int nb) {
    int t = threadIdx.x;            // 64 threads
    int carry = 0;
    for (int base = 0; base < nb; base += 64) {
        int i = base + t;
        int v = (i < nb) ? bsum[i] : 0;
        int s = v;
        #pragma unroll
        for (int off = 1; off < 64; off <<= 1) {
            int u = __shfl_up(s, off, 64);
            if (t >= off) s += u;
        }
        if (i < nb) bofs[i] = s - v + carry;
        int tot = __shfl(s, 63, 64);
        carry += tot;
    }
}

__global__ __launch_bounds__(256) void scan_p3(const int* __restrict__ deg,
                                               const int* __restrict__ bofs,
                                               int* __restrict__ row_start, int N) {
    int t = threadIdx.x;
    int idx = blockIdx.x * 1024 + t * 4;
    int4 v = load_deg4(deg, idx, N);
    int tsum = v.x + v.y + v.z + v.w;
    int s = tsum;
    const int lane = t & 63, w = t >> 6;
    #pragma unroll
    for (int off = 1; off < 64; off <<= 1) {
        int u = __shfl_up(s, off, 64);
        if (lane >= off) s += u;
    }
    __shared__ int ws[4];
    if (lane == 63) ws[w] = s;
    __syncthreads();
    int wadd = 0;
    if (w > 0) wadd += ws[0];
    if (w > 1) wadd += ws[1];
    if (w > 2) wadd += ws[2];
    int p = (s - tsum) + wadd + bofs[blockIdx.x];
    if (idx < N)     { p += v.x; row_start[idx + 1] = p; }
    if (idx + 1 < N) { p += v.y; row_start[idx + 2] = p; }
    if (idx + 2 < N) { p += v.z; row_start[idx + 3] = p; }
    if (idx + 3 < N) { p += v.w; row_start[idx + 4] = p; }
    if (blockIdx.x == 0 && t == 0) row_start[0] = 0;
}

__global__ void scatter_edges(const int* __restrict__ src, const int* __restrict__ dst,
                              const int* __restrict__ row_start, int* __restrict__ cursor,
                              int* __restrict__ esrc, int E, int N)
{
    int i = blockIdx.x * blockDim.x + threadIdx.x;
    int total = E + N;
    if (i >= total) return;
    int s, d;
    if (i < E) { s = src[i]; d = dst[i]; }
    else       { s = i - E;  d = s; }              // self loops
    int pos = row_start[d] + atomicAdd(&cursor[d], 1);
    esrc[pos] = s;
}

// ---------------- Kernel 5: per-node softmax-weighted aggregation ----------------
// One wave per dst node. Lane owns channels {2*lane, 2*lane+1} -> one head/lane.
// h gathered in bf16 (4 B/lane/edge).
__global__ __launch_bounds__(256) void gat_aggregate(
    const unsigned short* __restrict__ hb, const float* __restrict__ as_,
    const float* __restrict__ ad_, const int* __restrict__ row_start,
    const int* __restrict__ esrc, const float* __restrict__ bias,
    const float* __restrict__ x, float* __restrict__ out, int N)
{
    int wid = blockIdx.x * 4 + (threadIdx.x >> 6);
    int lane = threadIdx.x & 63;
    if (wid >= N) return;
    const int head = lane >> 4;                    // channel 2*lane -> head (2*lane)>>5
    const float adv = ad_[wid * 4 + head];

    float den = 0.f, acc0 = 0.f, acc1 = 0.f;
    const int jb = row_start[wid], je = row_start[wid + 1];
    int j = jb;
    for (; j + 3 < je; j += 4) {
        int s0 = esrc[j], s1 = esrc[j + 1], s2 = esrc[j + 2], s3 = esrc[j + 3];
        float e0 = as_[s0 * 4 + head] + adv;
        float e1 = as_[s1 * 4 + head] + adv;
        float e2 = as_[s2 * 4 + head] + adv;
        float e3 = as_[s3 * 4 + head] + adv;
        unsigned int h0 = *(const unsigned int*)&hb[(size_t)s0 * CH + 2 * lane];
        unsigned int h1 = *(const unsigned int*)&hb[(size_t)s1 * CH + 2 * lane];
        unsigned int h2 = *(const unsigned int*)&hb[(size_t)s2 * CH + 2 * lane];
        unsigned int h3 = *(const unsigned int*)&hb[(size_t)s3 * CH + 2 * lane];
        e0 = (e0 < 0.f) ? 0.2f * e0 : e0;  e1 = (e1 < 0.f) ? 0.2f * e1 : e1;
        e2 = (e2 < 0.f) ? 0.2f * e2 : e2;  e3 = (e3 < 0.f) ? 0.2f * e3 : e3;
        float p0 = __expf(e0), p1 = __expf(e1), p2 = __expf(e2), p3 = __expf(e3);
        den += (p0 + p1) + (p2 + p3);
        acc0 = fmaf(p0, bflo(h0), fmaf(p1, bflo(h1), fmaf(p2, bflo(h2), fmaf(p3, bflo(h3), acc0))));
        acc1 = fmaf(p0, bfhi(h0), fmaf(p1, bfhi(h1), fmaf(p2, bfhi(h2), fmaf(p3, bfhi(h3), acc1))));
    }
    for (; j < je; ++j) {
        int s0 = esrc[j];
        float e0 = as_[s0 * 4 + head] + adv;
        unsigned int h0 = *(const unsigned int*)&hb[(size_t)s0 * CH + 2 * lane];
        e0 = (e0 < 0.f) ? 0.2f * e0 : e0;
        float p0 = __expf(e0);
        den += p0;
        acc0 = fmaf(p0, bflo(h0), acc0);
        acc1 = fmaf(p0, bfhi(h0), acc1);
    }
    float inv = 1.f / (den + 1e-16f);
    float2 bv = *(const float2*)&bias[2 * lane];
    float o0 = acc0 * inv + bv.x;
    float o1 = acc1 * inv + bv.y;
    o0 = (o0 > 0.f) ? o0 : expm1f(o0);             // ELU
    o1 = (o1 > 0.f) ? o1 : expm1f(o1);
    float2 xv = *(const float2*)&x[(size_t)wid * CH + 2 * lane];
    float2 ov; ov.x = o0 + xv.x; ov.y = o1 + xv.y;
    *(float2*)&out[(size_t)wid * CH + 2 * lane] = ov;
}

extern "C" void kernel_launch(void* const* d_in, const int* in_sizes, int n_in,
                              void* d_out, int out_size, void* d_ws, size_t ws_size,
                              hipStream_t stream) {
    const float* x     = (const float*)d_in[0];
    const int*   ei    = (const int*)d_in[1];
    const float* W     = (const float*)d_in[2];
    const float* a_src = (const float*)d_in[3];
    const float* a_dst = (const float*)d_in[4];
    const float* bias  = (const float*)d_in[5];
    float* out = (float*)d_out;

    const int N = in_sizes[0] / CH;       // 50000
    const int E = in_sizes[1] / 2;        // 800000
    const int* src = ei;
    const int* dst = ei + E;

    unsigned short* hb = (unsigned short*)d_ws;            // N*128 bf16
    float* as_ = (float*)(hb + (size_t)N * CH);            // N*4
    float* ad_ = as_ + (size_t)N * 4;                      // N*4
    short* Wbf = (short*)(ad_ + (size_t)N * 4);            // 128*128
    int* deg       = (int*)(Wbf + CH * CH);
    int* cursor    = deg + N;
    int* row_start = cursor + N;
    int* esrc      = row_start + (N + 1);                  // E + N
    int* bsum      = esrc + (E + N);
    int* bofs      = bsum + 2048;

    const int NBLK = (N + 1023) / 1024;                    // 49

    prep<<<(N + 255) / 256, 256, 0, stream>>>(W, Wbf, deg, cursor, N);
    gemm_mfma<<<(N + 127) / 128, 256, 0, stream>>>(x, Wbf, a_src, a_dst, hb, as_, ad_, N);
    hist<<<(E / 4 + 255) / 256, 256, 0, stream>>>(dst, deg, E);
    scan_p1<<<NBLK, 256, 0, stream>>>(deg, bsum, N);
    scan_p2<<<1, 64, 0, stream>>>(bsum, bofs, NBLK);
    scan_p3<<<NBLK, 256, 0, stream>>>(deg, bofs, row_start, N);
    scatter_edges<<<(E + N + 255) / 256, 256, 0, stream>>>(src, dst, row_start, cursor, esrc, E, N);
    gat_aggregate<<<(N + 3) / 4, 256, 0, stream>>>(hb, as_, ad_, row_start, esrc, bias, x, out, N);
}